// Round 10
// baseline (438.466 us; speedup 1.0000x reference)
//
#include <hip/hip_runtime.h>
#include <hip/hip_fp16.h>

// DEQ classifier, 32x32x16 MFMA version (2x LDS intensity vs 16x16x32).
// One block per image (1024 x 256 threads, 4 waves; wave owns 8 output rows
// as two N-groups of 4). LDS: two planes of 8-channel f16 pixel bundles
// (16 B) on a 36x36 zero-padded grid, swizzle bofs(y,x)=((y*36+x)*16)^((x&8)<<1).
//   zxb: [z0..z4, img0..2]    hbb: [h0..h5, 0, 0]
// Conv as MFMA 32x32x16:
//   A[32 rows = dx*8+oc][16 k]  : weights in VGPRs (cw1/cw2, 20 frags each)
//   B[16 k][32 cols = ry*8+ax]  : pixel bundle at (ybase+ry+ty, 4ax+tx), 1 b128/lane
//   k = tp*8+ch, tap = 2c+tp over 5x8 window (ty=c>>2, tx=2(c&3)+tp); 20 chunks.
//   D: col=lane&31=(ry,ax), row=(reg&3)+8*(reg>>2)+4*(lane>>5) = dx*8+oc
//      (dx=reg>>2, oc=(reg&3)+4*hi)   [m74/m101-verified layout]
// GroupNorm: conv1 acc kept in regs across B1; normalized h written after the
// fold -> zero pads are exact, conv2 uses plain weights + plain bias.

typedef _Float16 half8 __attribute__((ext_vector_type(8)));
typedef float f32x16 __attribute__((ext_vector_type(16)));

__device__ __forceinline__ unsigned pk2(float a, float b) {
    __half2 h = __float22half2_rn(make_float2(a, b));
    return *reinterpret_cast<unsigned*>(&h);
}
__device__ __forceinline__ float2 up2(unsigned u) {
    __half2 h = *reinterpret_cast<__half2*>(&u);
    return __half22float2(h);
}
__device__ __forceinline__ float lrelu(float x) { return fmaxf(x, 0.01f * x); }
__device__ __forceinline__ int bofs(int y, int x) {
    return ((y * 36 + x) * 16) ^ ((x & 8) << 1);
}

// ---- prep: 32x32 A-fragments ----
// ws[0..5119]      : conv1 A-frags, 20 chunks x 64 lanes x 4 dw
//   lane l: m=l&31 (dx=m>>3, oc=m&7), tp=l>>5; tap=2c+tp (ty=tap>>3, tx=tap&7)
//   elem j = ch j: w1[oc][ch][ty][tx-dx], 0 if oc>=6 or tx-dx not in [0,5)
// ws[5120..10239]  : conv2 A-frags from w2 (0 if oc>=5 or ch>=6)
__global__ void pack_weights(const float* __restrict__ w1,
                             const float* __restrict__ w2,
                             unsigned* __restrict__ ws)
{
    int t = blockIdx.x * 256 + threadIdx.x;
    if (t < 1280) {
        int c = t >> 6, l = t & 63;
        int m = l & 31, tp = l >> 5;
        int dx = m >> 3, oc = m & 7;
        int tap = 2 * c + tp, ty = tap >> 3, tx = tap & 7, kx = tx - dx;
        unsigned q[4];
        #pragma unroll
        for (int d = 0; d < 4; ++d) {
            float v0 = 0.f, v1 = 0.f;
            if (oc < 6 && kx >= 0 && kx < 5) {
                v0 = w1[((oc * 8 + 2 * d) * 5 + ty) * 5 + kx];
                v1 = w1[((oc * 8 + 2 * d + 1) * 5 + ty) * 5 + kx];
            }
            q[d] = pk2(v0, v1);
        }
        *(uint4*)&ws[t * 4] = make_uint4(q[0], q[1], q[2], q[3]);
    } else if (t < 2560) {
        int u = t - 1280;
        int c = u >> 6, l = u & 63;
        int m = l & 31, tp = l >> 5;
        int dx = m >> 3, oc = m & 7;
        int tap = 2 * c + tp, ty = tap >> 3, tx = tap & 7, kx = tx - dx;
        unsigned q[4];
        #pragma unroll
        for (int d = 0; d < 4; ++d) {
            float v0 = 0.f, v1 = 0.f;
            if (oc < 5 && kx >= 0 && kx < 5) {
                if (2 * d < 6)     v0 = w2[((oc * 6 + 2 * d) * 5 + ty) * 5 + kx];
                if (2 * d + 1 < 6) v1 = w2[((oc * 6 + 2 * d + 1) * 5 + ty) * 5 + kx];
            }
            q[d] = pk2(v0, v1);
        }
        *(uint4*)&ws[5120 + u * 4] = make_uint4(q[0], q[1], q[2], q[3]);
    }
}

__global__ __launch_bounds__(256, 2)
void deq_kernel(const float* __restrict__ image,
                const unsigned* __restrict__ wks,
                const float* __restrict__ b1,
                const float* __restrict__ gam, const float* __restrict__ bet,
                const float* __restrict__ b2,
                const float* __restrict__ wh, const float* __restrict__ bh,
                float* __restrict__ out)
{
    __shared__ __align__(16) unsigned zxb[36 * 36 * 4];
    __shared__ __align__(16) unsigned hbb[36 * 36 * 4];
    __shared__ float red[48];

    const int n    = blockIdx.x;
    const int tid  = threadIdx.x;
    const int lane = tid & 63;
    const int wid  = tid >> 6;          // 0..3: wave owns output rows wid*8..+7
    const int nidx = lane & 31;         // MFMA column
    const int ax   = nidx & 7;          // anchor-of-4px within row
    const int ry   = nidx >> 3;         // row within N-group
    const int hi   = lane >> 5;         // k-half / oc-half selector

    for (int p = tid; p < 36 * 36 * 4; p += 256) { zxb[p] = 0u; hbb[p] = 0u; }
    __syncthreads();

    {   // image -> bundle ch 5..7 (each thread one 1x4 strip)
        const int yy = tid >> 3, xx0 = (tid & 7) << 2;
        float4 i0 = *(const float4*)&image[(n * 3 + 0) * 1024 + yy * 32 + xx0];
        float4 i1 = *(const float4*)&image[(n * 3 + 1) * 1024 + yy * 32 + xx0];
        float4 i2 = *(const float4*)&image[(n * 3 + 2) * 1024 + yy * 32 + xx0];
        float a0[4] = {i0.x, i0.y, i0.z, i0.w};
        float a1[4] = {i1.x, i1.y, i1.z, i1.w};
        float a2[4] = {i2.x, i2.y, i2.z, i2.w};
        #pragma unroll
        for (int i = 0; i < 4; ++i) {
            unsigned* bp = (unsigned*)((char*)zxb + bofs(yy + 2, xx0 + 2 + i));
            bp[2] = pk2(0.f, a0[i]);
            bp[3] = pk2(a1[i], a2[i]);
        }
    }

    // weight A-fragments in registers (2 x 20 x 4 = 160 VGPR)
    uint4 cw1[20], cw2[20];
    #pragma unroll
    for (int c = 0; c < 20; ++c) {
        cw1[c] = *(const uint4*)&wks[(c * 64 + lane) * 4];
        cw2[c] = *(const uint4*)&wks[5120 + (c * 64 + lane) * 4];
    }
    // swizzled x-offsets: chunk c reads x = 4ax + 2(c&3) + tp, ty = c>>2
    int sx[4];
    #pragma unroll
    for (int i = 0; i < 4; ++i) {
        int xr = 4 * ax + hi + 2 * i;
        sx[i] = (xr * 16) ^ ((xr & 8) << 1);
    }

    float b1q[4], b2q[4];
    #pragma unroll
    for (int j = 0; j < 4; ++j) {
        int oc = 4 * hi + j;
        b1q[j] = (oc < 6) ? b1[oc] : 0.f;
        b2q[j] = (oc < 5) ? b2[oc] : 0.f;
    }

    __syncthreads();

    const char* zb = (const char*)zxb;
    const char* hb = (const char*)hbb;
    const int base0 = (wid * 8 + ry) * 576;       // N-group 0 plane-row base
    const int base1 = base0 + 4 * 576;            // N-group 1

    #pragma unroll 1
    for (int it = 0; it < 30; ++it) {
        // ================= conv1 (20 chunks x 2 N-groups) =================
        f32x16 acc[2];
        #pragma unroll
        for (int g = 0; g < 2; ++g)
            #pragma unroll
            for (int r = 0; r < 16; ++r) acc[g][r] = b1q[r & 3];
        #pragma unroll
        for (int c = 0; c < 20; ++c) {
            half8 wf = __builtin_bit_cast(half8, cw1[c]);
            const int off = (c >> 2) * 576 + sx[c & 3];
            half8 p0 = *(const half8*)(zb + base0 + off);
            acc[0] = __builtin_amdgcn_mfma_f32_32x32x16_f16(wf, p0, acc[0], 0, 0, 0);
            half8 p1 = *(const half8*)(zb + base1 + off);
            acc[1] = __builtin_amdgcn_mfma_f32_32x32x16_f16(wf, p1, acc[1], 0, 0, 0);
        }

        // ---- leaky (kept in regs) + GN partial stats ----
        float ps_a = 0.f, pq_a = 0.f, ps_b = 0.f, pq_b = 0.f;
        #pragma unroll
        for (int g = 0; g < 2; ++g)
            #pragma unroll
            for (int r = 0; r < 16; ++r) {
                float v = lrelu(acc[g][r]);
                acc[g][r] = v;
                if ((r & 3) < 2) { ps_a += v; pq_a = fmaf(v, v, pq_a); }
                else             { ps_b += v; pq_b = fmaf(v, v, pq_b); }
            }
        // hi=0: (a,b)=(g0,g1); hi=1: a=g2, b=junk(oc6,7 all-zero anyway)
        #pragma unroll
        for (int m = 1; m <= 16; m <<= 1) {
            ps_a += __shfl_xor(ps_a, m); pq_a += __shfl_xor(pq_a, m);
            ps_b += __shfl_xor(ps_b, m); pq_b += __shfl_xor(pq_b, m);
        }
        if (lane == 0)  { red[wid * 8 + 0] = ps_a; red[wid * 8 + 1] = ps_b;
                          red[wid * 8 + 4] = pq_a; red[wid * 8 + 5] = pq_b; }
        if (lane == 32) { red[wid * 8 + 2] = ps_a; red[wid * 8 + 6] = pq_a; }
        __syncthreads();                               // B1

        // ---- GN fold (every thread; broadcast reads) ----
        float scv[8], shv[8];
        #pragma unroll
        for (int g3 = 0; g3 < 3; ++g3) {
            float s = 0.f, q = 0.f;
            #pragma unroll
            for (int w = 0; w < 4; ++w) { s += red[w * 8 + g3]; q += red[w * 8 + 4 + g3]; }
            float mean = s * (1.f / 2048.f);
            float var  = q * (1.f / 2048.f) - mean * mean;
            float inv  = rsqrtf(var + 1e-5f);
            #pragma unroll
            for (int k = 0; k < 2; ++k) {
                int c = 2 * g3 + k;
                scv[c] = inv * gam[c];
                shv[c] = bet[c] - mean * scv[c];
            }
        }
        scv[6] = scv[7] = shv[6] = shv[7] = 0.f;

        // ---- write normalized h (zero pads stay exact) ----
        #pragma unroll
        for (int g = 0; g < 2; ++g) {
            const int yrow = wid * 8 + g * 4 + ry + 2;
            #pragma unroll
            for (int d = 0; d < 4; ++d) {
                float h0 = fmaf(acc[g][4 * d + 0], scv[4 * hi + 0], shv[4 * hi + 0]);
                float h1 = fmaf(acc[g][4 * d + 1], scv[4 * hi + 1], shv[4 * hi + 1]);
                float h2 = fmaf(acc[g][4 * d + 2], scv[4 * hi + 2], shv[4 * hi + 2]);
                float h3 = fmaf(acc[g][4 * d + 3], scv[4 * hi + 3], shv[4 * hi + 3]);
                char* wp = (char*)hbb + bofs(yrow, 4 * ax + d + 2) + hi * 8;
                *(uint2*)wp = make_uint2(pk2(h0, h1), pk2(h2, h3));
            }
        }
        __syncthreads();                               // B2

        // ================= conv2 (plain weights, plain bias) =================
        #pragma unroll
        for (int g = 0; g < 2; ++g)
            #pragma unroll
            for (int r = 0; r < 16; ++r) acc[g][r] = b2q[r & 3];
        #pragma unroll
        for (int c = 0; c < 20; ++c) {
            half8 wf = __builtin_bit_cast(half8, cw2[c]);
            const int off = (c >> 2) * 576 + sx[c & 3];
            half8 p0 = *(const half8*)(hb + base0 + off);
            acc[0] = __builtin_amdgcn_mfma_f32_32x32x16_f16(wf, p0, acc[0], 0, 0, 0);
            half8 p1 = *(const half8*)(hb + base1 + off);
            acc[1] = __builtin_amdgcn_mfma_f32_32x32x16_f16(wf, p1, acc[1], 0, 0, 0);
        }

        // ---- leaky + damped z RMW ----
        #pragma unroll
        for (int g = 0; g < 2; ++g) {
            const int yrow = wid * 8 + g * 4 + ry + 2;
            #pragma unroll
            for (int d = 0; d < 4; ++d) {
                char* zp = (char*)zxb + bofs(yrow, 4 * ax + d + 2);
                if (hi == 0) {        // oc 0..3 = z0..z3: b64 RMW
                    uint2 zo = *(uint2*)zp;
                    float2 za = up2(zo.x), zc = up2(zo.y);
                    float z0 = 0.5f * za.x + 0.5f * lrelu(acc[g][4 * d + 0]);
                    float z1 = 0.5f * za.y + 0.5f * lrelu(acc[g][4 * d + 1]);
                    float z2 = 0.5f * zc.x + 0.5f * lrelu(acc[g][4 * d + 2]);
                    float z3 = 0.5f * zc.y + 0.5f * lrelu(acc[g][4 * d + 3]);
                    *(uint2*)zp = make_uint2(pk2(z0, z1), pk2(z2, z3));
                } else {              // oc4 = z4: u16 RMW (img0 in hi half untouched)
                    _Float16* pz = (_Float16*)(zp + 8);
                    float z4 = 0.5f * (float)pz[0] + 0.5f * lrelu(acc[g][4 * d + 0]);
                    pz[0] = (_Float16)z4;
                }
            }
        }
        __syncthreads();                               // B3
    }

    // ================= head: out[o] = <z, wh[o]> + bh[o] =================
    {
        const int yy = tid >> 3, xx0 = (tid & 7) << 2;
        float zf[5][4];
        #pragma unroll
        for (int i = 0; i < 4; ++i) {
            const unsigned* bp = (const unsigned*)((const char*)zxb + bofs(yy + 2, xx0 + 2 + i));
            float2 f0 = up2(bp[0]), f1 = up2(bp[1]), f2 = up2(bp[2]);
            zf[0][i] = f0.x; zf[1][i] = f0.y; zf[2][i] = f1.x; zf[3][i] = f1.y; zf[4][i] = f2.x;
        }
        float ho[10];
        #pragma unroll
        for (int o = 0; o < 10; ++o) ho[o] = 0.f;
        #pragma unroll
        for (int c = 0; c < 5; ++c) {
            #pragma unroll
            for (int o = 0; o < 10; ++o) {
                float4 wv = *(const float4*)&wh[(o * 5 + c) * 1024 + yy * 32 + xx0];
                ho[o] = fmaf(zf[c][0], wv.x, ho[o]);
                ho[o] = fmaf(zf[c][1], wv.y, ho[o]);
                ho[o] = fmaf(zf[c][2], wv.z, ho[o]);
                ho[o] = fmaf(zf[c][3], wv.w, ho[o]);
            }
        }
        #pragma unroll
        for (int m = 1; m < 64; m <<= 1) {
            #pragma unroll
            for (int o = 0; o < 10; ++o) ho[o] += __shfl_xor(ho[o], m);
        }
        if (lane == 0) {
            #pragma unroll
            for (int o = 0; o < 10; ++o) red[wid * 10 + o] = ho[o];
        }
    }
    __syncthreads();
    if (tid < 10)
        out[n * 10 + tid] = red[tid] + red[10 + tid] + red[20 + tid] + red[30 + tid] + bh[tid];
}

extern "C" void kernel_launch(void* const* d_in, const int* in_sizes, int n_in,
                              void* d_out, int out_size, void* d_ws, size_t ws_size,
                              hipStream_t stream) {
    const float* image = (const float*)d_in[0];
    const float* w1    = (const float*)d_in[1];
    const float* b1    = (const float*)d_in[2];
    const float* gam   = (const float*)d_in[3];
    const float* bet   = (const float*)d_in[4];
    const float* w2    = (const float*)d_in[5];
    const float* b2    = (const float*)d_in[6];
    const float* wh    = (const float*)d_in[7];
    const float* bh    = (const float*)d_in[8];
    float* out = (float*)d_out;
    unsigned* ws = (unsigned*)d_ws;

    pack_weights<<<10, 256, 0, stream>>>(w1, w2, ws);

    const int N = in_sizes[0] / (3 * 32 * 32);   // 1024 images
    deq_kernel<<<N, 256, 0, stream>>>(image, ws, b1, gam, bet, b2, wh, bh, out);
}